// Round 2
// 770.349 us; speedup vs baseline: 1.2855x; 1.2855x over previous
//
#include <hip/hip_runtime.h>

#define NH 8
#define DH 32
#define ROWS 128          // tokens per block (16 batches x 8 tokens)
#define SLD 36            // q/k/v slab leading dim (8B-aligned rows, bank stagger)

typedef __attribute__((ext_vector_type(8))) short bf16x8;
typedef __attribute__((ext_vector_type(4))) float f32x4;

__device__ __forceinline__ unsigned short f2bf(float f) {
  // round-to-nearest-even bf16 (finite inputs only)
  unsigned u = __float_as_uint(f);
  u = (u + 0x7fffu + ((u >> 16) & 1u)) >> 16;
  return (unsigned short)u;
}

// async 16B/lane global->LDS (wave-uniform LDS base, per-lane global addr)
__device__ __forceinline__ void gload16(const void* g, void* l) {
  __builtin_amdgcn_global_load_lds((const __attribute__((address_space(1))) void*)g,
                                   (__attribute__((address_space(3))) void*)l, 16, 0, 0);
}

// 8 consecutive bf16 (8B-aligned) -> 8 fp32, 1 VALU op per element
__device__ __forceinline__ void ld_bf8(const unsigned short* p, float* f) {
  const uint2 a = *(const uint2*)(p);
  const uint2 b = *(const uint2*)(p + 4);
  f[0] = __uint_as_float(a.x << 16); f[1] = __uint_as_float(a.x & 0xffff0000u);
  f[2] = __uint_as_float(a.y << 16); f[3] = __uint_as_float(a.y & 0xffff0000u);
  f[4] = __uint_as_float(b.x << 16); f[5] = __uint_as_float(b.x & 0xffff0000u);
  f[6] = __uint_as_float(b.y << 16); f[7] = __uint_as_float(b.y & 0xffff0000u);
}

// ---------------- prep: coalesced LDS transpose + cast, gather bias matrix ----------------
// grid 65: blocks 0..47 = wqkv 64x64 tiles (4k x 12n), 48..63 = wout tiles (4x4), 64 = bias
__global__ void prep_kernel(const float* __restrict__ wqkv, const float* __restrict__ wout,
                            const float* __restrict__ table, const int* __restrict__ relidx,
                            unsigned short* __restrict__ wqkvT, unsigned short* __restrict__ woutT,
                            float* __restrict__ biasM) {
  __shared__ float T[64][65];
  const int b = blockIdx.x, tid = threadIdx.x;
  if (b == 64) {
    for (int e = tid; e < 512; e += 256) {
      const int hh = e >> 6, ij = e & 63;
      biasM[e] = table[relidx[ij] * NH + hh];   // biasM[h][i*8+j]
    }
    return;
  }
  const float* src; unsigned short* dst; int N, k0, n0;
  if (b < 48) { src = wqkv; dst = wqkvT; N = 768; k0 = (b / 12) * 64; n0 = (b % 12) * 64; }
  else { const int bb = b - 48; src = wout; dst = woutT; N = 256; k0 = (bb >> 2) * 64; n0 = (bb & 3) * 64; }
  const int c = tid & 63, rb = (tid >> 6) * 16;
  #pragma unroll
  for (int p = 0; p < 16; ++p)
    T[c][rb + p] = src[(size_t)(k0 + rb + p) * N + n0 + c];   // coalesced read; T[n_loc][k_loc]
  __syncthreads();
  const int r = tid >> 2, cc = (tid & 3) * 16;
  union { unsigned short e[16]; uint4 q[2]; } u;
  #pragma unroll
  for (int j = 0; j < 16; ++j) u.e[j] = f2bf(T[r][cc + j]);
  uint4* dq = (uint4*)&dst[(size_t)(n0 + r) * 256 + k0 + cc]; // dst[n][k], 32B/lane contiguous
  dq[0] = u.q[0]; dq[1] = u.q[1];
}

// ---------------- fused main kernel ----------------
// LDS budget: stage 49152 + 3*9216 slabs + 2048 bias = 78848 B -> 2 blocks/CU
__global__ __launch_bounds__(256, 2)
void attn_main(const float* __restrict__ x,
               const float* __restrict__ ln_w,
               const float* __restrict__ ln_b,
               const unsigned short* __restrict__ wqkvT,
               const unsigned short* __restrict__ woutT,
               const float* __restrict__ biasM,
               float* __restrict__ out) {
  __shared__ unsigned short s_stage[96 * 256];   // unpadded rows; slot-XOR swizzled contents
  __shared__ unsigned short s_q[ROWS * SLD];
  __shared__ unsigned short s_k[ROWS * SLD];
  __shared__ unsigned short s_v[ROWS * SLD];
  __shared__ float s_bias[NH * 64];

  const int tid  = threadIdx.x;
  const int w    = tid >> 6;        // wave 0..3
  const int lane = tid & 63;
  const int l15  = lane & 15;
  const int l7   = lane & 7;
  const int quad = lane >> 4;
  const int row0 = blockIdx.x * ROWS;

  // --- async stagers. LDS row r holds global slot (s ^ (r&7)) at slot s -> reads XOR back.
  auto stage_qkv = [&](int hh) {     // 96 rows of head hh's W_qkv^T (q16|q16|k16|k16|v16|v16)
    #pragma unroll
    for (int it = 0; it < 12; ++it) {
      const int r  = w * 24 + it * 2 + (lane >> 5);
      const int sg = ((lane & 31) ^ (r & 7)) << 3;              // swizzled global slot (ushorts)
      const int gRow = ((r >> 5) << 8) + hh * 32 + (r & 31);
      gload16(wqkvT + (size_t)gRow * 256 + sg, &s_stage[(w * 24 + it * 2) * 256]);
    }
  };
  auto stage_out = [&](int pp) {     // 64 rows of w_out^T chunk pp
    #pragma unroll
    for (int it = 0; it < 8; ++it) {
      const int r  = w * 16 + it * 2 + (lane >> 5);
      const int sg = ((lane & 31) ^ (r & 7)) << 3;
      gload16(woutT + (size_t)((pp) * 64 + r) * 256 + sg, &s_stage[(w * 16 + it * 2) * 256]);
    }
  };

  stage_qkv(0);   // in flight under LayerNorm
  for (int e = tid; e < 512; e += 256) s_bias[e] = biasM[e];

  // ---- LayerNorm directly into register-resident A-fragments ----
  // lane holds A[m=l15][k=quad*8+j] for kstep kk; wave w owns m-tiles {2w, 2w+1}
  bf16x8 afrag[2][8];
  #pragma unroll
  for (int mt = 0; mt < 2; ++mt) {
    const int lrow = (2 * w + mt) * 16 + l15;
    const float* xr = x + (size_t)(row0 + lrow) * 256;
    float4 xv[16];
    float sum = 0.f, ss = 0.f;
    #pragma unroll
    for (int kk = 0; kk < 8; ++kk) {
      #pragma unroll
      for (int i = 0; i < 2; ++i) {
        const float4 v = *(const float4*)(xr + kk * 32 + quad * 8 + i * 4);
        xv[kk * 2 + i] = v;
        sum += v.x + v.y + v.z + v.w;
        ss  += v.x * v.x + v.y * v.y + v.z * v.z + v.w * v.w;
      }
    }
    sum += __shfl_xor(sum, 16); ss += __shfl_xor(ss, 16);
    sum += __shfl_xor(sum, 32); ss += __shfl_xor(ss, 32);
    const float mean = sum * (1.f / 256.f);
    const float var  = ss * (1.f / 256.f) - mean * mean;
    const float rstd = rsqrtf(var + 1e-5f);
    #pragma unroll
    for (int kk = 0; kk < 8; ++kk) {
      union { bf16x8 v; unsigned short e[8]; } pk;
      #pragma unroll
      for (int i = 0; i < 2; ++i) {
        const float4 g   = *(const float4*)(ln_w + kk * 32 + quad * 8 + i * 4);
        const float4 bta = *(const float4*)(ln_b + kk * 32 + quad * 8 + i * 4);
        const float4 v = xv[kk * 2 + i];
        pk.e[i * 4 + 0] = f2bf((v.x - mean) * rstd * g.x + bta.x);
        pk.e[i * 4 + 1] = f2bf((v.y - mean) * rstd * g.y + bta.y);
        pk.e[i * 4 + 2] = f2bf((v.z - mean) * rstd * g.z + bta.z);
        pk.e[i * 4 + 3] = f2bf((v.w - mean) * rstd * g.w + bta.w);
      }
      afrag[mt][kk] = pk.v;
    }
  }
  __syncthreads();   // stage(0) landed (vmcnt drained at barrier) + bias visible

  // attention output in MFMA-A-fragment layout: ao[mt][h] = dims quad*8..+8 of row (2w+mt)*16+l15
  bf16x8 ao[2][NH];

  #pragma unroll
  for (int h = 0; h < NH; ++h) {
    // ---- QKV MFMA for head h (reads swizzled s_stage) ----
    const f32x4 fz = {0.f, 0.f, 0.f, 0.f};
    f32x4 acc[2][6];
    #pragma unroll
    for (int mt = 0; mt < 2; ++mt)
      #pragma unroll
      for (int t = 0; t < 6; ++t) acc[mt][t] = fz;

    #pragma unroll
    for (int kk = 0; kk < 8; ++kk) {
      const int bs = (((kk << 2) + quad) ^ l7) << 3;   // swizzled slot, row n&7 == l15&7
      const bf16x8 a0 = afrag[0][kk];
      const bf16x8 a1 = afrag[1][kk];
      #pragma unroll
      for (int t = 0; t < 6; ++t) {
        const bf16x8 b = *(const bf16x8*)&s_stage[(t * 16 + l15) * 256 + bs];
        acc[0][t] = __builtin_amdgcn_mfma_f32_16x16x32_bf16(a0, b, acc[0][t], 0, 0, 0);
        acc[1][t] = __builtin_amdgcn_mfma_f32_16x16x32_bf16(a1, b, acc[1][t], 0, 0, 0);
      }
    }

    // C layout: col=l15, row=quad*4+r -> scatter to q/k/v slabs (bf16), scale folded into q
    #pragma unroll
    for (int mt = 0; mt < 2; ++mt) {
      #pragma unroll
      for (int t = 0; t < 6; ++t) {
        const int s = t >> 1, u = t & 1;
        unsigned short* slab = (s == 0) ? s_q : (s == 1) ? s_k : s_v;
        const float mul = (s == 0) ? 0.17677669529663687f : 1.f;
        #pragma unroll
        for (int r = 0; r < 4; ++r) {
          const int row = (2 * w + mt) * 16 + quad * 4 + r;
          slab[row * SLD + u * 16 + l15] = f2bf(acc[mt][t][r] * mul);
        }
      }
    }
    __syncthreads();   // slabs visible; all s_stage reads done

    // issue next weight stage NOW -> HBM/L2 latency hides under attention
    if (h < NH - 1) stage_qkv(h + 1); else stage_out(0);

    // ---- attention: thread owns rows (2w+mt)*16+l15, dims quad*8..+8 ----
    const float4 bb0 = *(const float4*)&s_bias[h * 64 + l7 * 8];
    const float4 bb1 = *(const float4*)&s_bias[h * 64 + l7 * 8 + 4];
    #pragma unroll
    for (int mt = 0; mt < 2; ++mt) {
      const int i  = (2 * w + mt) * 16 + l15;
      const int bl = i >> 3;
      const int kbase = (bl * 8) * SLD + quad * 8;
      float q8[8];
      ld_bf8(&s_q[i * SLD + quad * 8], q8);
      float sc[8];
      #pragma unroll
      for (int j = 0; j < 8; ++j) {
        float k8[8];
        ld_bf8(&s_k[kbase + j * SLD], k8);
        sc[j] = q8[0]*k8[0] + q8[1]*k8[1] + q8[2]*k8[2] + q8[3]*k8[3]
              + q8[4]*k8[4] + q8[5]*k8[5] + q8[6]*k8[6] + q8[7]*k8[7];
      }
      // reduce partial dots across the 4 quads holding this row
      #pragma unroll
      for (int j = 0; j < 8; ++j) sc[j] += __shfl_xor(sc[j], 16);
      #pragma unroll
      for (int j = 0; j < 8; ++j) sc[j] += __shfl_xor(sc[j], 32);
      sc[0] += bb0.x; sc[1] += bb0.y; sc[2] += bb0.z; sc[3] += bb0.w;
      sc[4] += bb1.x; sc[5] += bb1.y; sc[6] += bb1.z; sc[7] += bb1.w;
      float mx = fmaxf(fmaxf(fmaxf(sc[0], sc[1]), fmaxf(sc[2], sc[3])),
                       fmaxf(fmaxf(sc[4], sc[5]), fmaxf(sc[6], sc[7])));
      float ex[8], sumw = 0.f;
      #pragma unroll
      for (int j = 0; j < 8; ++j) { ex[j] = __expf(sc[j] - mx); sumw += ex[j]; }
      const float inv = 1.f / sumw;
      float o8[8] = {0.f, 0.f, 0.f, 0.f, 0.f, 0.f, 0.f, 0.f};
      #pragma unroll
      for (int j = 0; j < 8; ++j) {
        const float p = ex[j] * inv;
        float v8[8];
        ld_bf8(&s_v[kbase + j * SLD], v8);
        o8[0] += p * v8[0]; o8[1] += p * v8[1]; o8[2] += p * v8[2]; o8[3] += p * v8[3];
        o8[4] += p * v8[4]; o8[5] += p * v8[5]; o8[6] += p * v8[6]; o8[7] += p * v8[7];
      }
      union { bf16x8 v; unsigned u[4]; } pk;
      #pragma unroll
      for (int d2 = 0; d2 < 4; ++d2)
        pk.u[d2] = (unsigned)f2bf(o8[2 * d2]) | ((unsigned)f2bf(o8[2 * d2 + 1]) << 16);
      ao[mt][h] = pk.v;
    }
    __syncthreads();   // next stage landed; attention slab reads done
  }

  // ---- output projection: out = ao @ w_out, A-fragments straight from registers ----
  // s_stage chunk p holds w_out^T rows [p*64, p*64+64) (stage_out(0) already visible)
  for (int p = 0; p < 4; ++p) {
    const f32x4 fz = {0.f, 0.f, 0.f, 0.f};
    f32x4 oacc[2][4];
    #pragma unroll
    for (int mt = 0; mt < 2; ++mt)
      #pragma unroll
      for (int nt = 0; nt < 4; ++nt) oacc[mt][nt] = fz;

    #pragma unroll
    for (int kk = 0; kk < 8; ++kk) {     // kstep == head
      const int bs = (((kk << 2) + quad) ^ l7) << 3;
      const bf16x8 a0 = ao[0][kk];
      const bf16x8 a1 = ao[1][kk];
      #pragma unroll
      for (int nt = 0; nt < 4; ++nt) {
        const bf16x8 b = *(const bf16x8*)&s_stage[(nt * 16 + l15) * 256 + bs];
        oacc[0][nt] = __builtin_amdgcn_mfma_f32_16x16x32_bf16(a0, b, oacc[0][nt], 0, 0, 0);
        oacc[1][nt] = __builtin_amdgcn_mfma_f32_16x16x32_bf16(a1, b, oacc[1][nt], 0, 0, 0);
      }
    }
    if (p < 3) {
      __syncthreads();      // all s_stage reads of chunk p done
      stage_out(p + 1);     // in flight under the C-write below
    }
    #pragma unroll
    for (int mt = 0; mt < 2; ++mt)
      #pragma unroll
      for (int nt = 0; nt < 4; ++nt)
        #pragma unroll
        for (int r = 0; r < 4; ++r) {
          const int grow = row0 + (2 * w + mt) * 16 + quad * 4 + r;
          out[(size_t)grow * 256 + p * 64 + nt * 16 + l15] = oacc[mt][nt][r];
        }
    if (p < 3) __syncthreads();   // chunk p+1 landed
  }
}

extern "C" void kernel_launch(void* const* d_in, const int* in_sizes, int n_in,
                              void* d_out, int out_size, void* d_ws, size_t ws_size,
                              hipStream_t stream) {
  const float* x      = (const float*)d_in[0];
  const float* ln_w   = (const float*)d_in[1];
  const float* ln_b   = (const float*)d_in[2];
  const float* wqkv   = (const float*)d_in[3];
  const float* wout   = (const float*)d_in[4];
  const float* table  = (const float*)d_in[5];
  const int*   relidx = (const int*)d_in[6];
  float* out = (float*)d_out;

  unsigned short* wqkvT = (unsigned short*)d_ws;        // 768*256 bf16
  unsigned short* woutT = wqkvT + 768 * 256;            // 256*256 bf16
  float* biasM = (float*)(woutT + 256 * 256);           // 8*64 fp32

  prep_kernel<<<65, 256, 0, stream>>>(wqkv, wout, table, relidx, wqkvT, woutT, biasM);
  attn_main<<<2048, 256, 0, stream>>>(x, ln_w, ln_b, wqkvT, woutT, biasM, out);
}